// Round 8
// baseline (416.677 us; speedup 1.0000x reference)
//
#include <hip/hip_runtime.h>
#include <hip/hip_bf16.h>
#include <stdint.h>

#define N_NODES 8192
#define IN_F    256
#define OUT_F   64
#define NEG_SLOPE 0.2f
#define CAP     512       // per-wave neighbor list; mean degree 82, sd 9 -> 47 sigma
#define DET_WORDS  4096   // 16 KB adjacency prefix scanned per block (L2-cached)
#define DET_HALVES 8192   // 16 KB X prefix scanned per block

// ws layout
#define SI_OFF    0
#define SJ_OFF    32768
#define PROJ_OFF  65536
#define FLAG_OFF  ((4 << 20) - 64)   // [0]=adj width, [1]=x-is-fp32
#define BM_OFF    (4 << 20)          // 8 MB bitmask

static __device__ __forceinline__ float bf2f(unsigned short u) {
    union { unsigned int i; float f; } v; v.i = ((unsigned int)u) << 16; return v.f;
}
static __device__ __forceinline__ float bflo(unsigned int u) {
    union { unsigned int i; float f; } v; v.i = u << 16; return v.f;
}
static __device__ __forceinline__ float bfhi(unsigned int u) {
    union { unsigned int i; float f; } v; v.i = u & 0xFFFF0000u; return v.f;
}
static __device__ __forceinline__ unsigned short f2bf(float f) {
    union { float f; unsigned int i; } v; v.f = f;
    unsigned int x = v.i;
    unsigned int lsb = (x >> 16) & 1u;
    x += 0x7FFFu + lsb;
    return (unsigned short)(x >> 16);
}

// Adjacency width detection on shared 16KB prefix. bit0 = not 4-byte elems,
// bit1 = not 2-byte, bit2 = not 1-byte. (R5 FETCH=167MB => width 4 here.)
static __device__ __forceinline__ int adj_viol_local(const unsigned int* w, int tid) {
    int viol = 0;
    for (int i = tid; i < DET_WORDS; i += 256) {
        unsigned int v = w[i];
        if (v) {
            if (v != 1u && v != 0x3F800000u) viol |= 1;
            unsigned int h0 = v & 0xFFFFu, h1 = v >> 16;
            if ((h0 != 0u && h0 != 1u && h0 != 0x3F80u) ||
                (h1 != 0u && h1 != 1u && h1 != 0x3F80u)) viol |= 2;
            unsigned int b0 = v & 0xFFu, b1 = (v >> 8) & 0xFFu,
                         b2 = (v >> 16) & 0xFFu, b3 = v >> 24;
            if (b0 > 1u || b1 > 1u || b2 > 1u || b3 > 1u) viol |= 4;
        }
    }
    return viol;
}

// X dtype: nonzero => fp32 (bf16-exponent >= 133 occurs w.p. ~0.48 per fp32
// mantissa half, never in bf16 N(0,1)). R5: fp32 for this harness.
static __device__ __forceinline__ int x_is_f32_local(const unsigned short* x, int tid) {
    int viol = 0;
    for (int i = tid; i < DET_HALVES; i += 256) {
        unsigned int e = ((unsigned int)x[i] >> 7) & 0xFFu;
        if (e >= 133u) viol = 1;
    }
    return viol;
}

static __device__ __forceinline__ void block_or(int v, int tid, int* sdet, int slot) {
    for (int o = 32; o; o >>= 1) v |= __shfl_xor(v, o, 64);
    if ((tid & 63) == 0 && v) atomicOr(&sdet[slot], v);
}

// ---------------------------------------------------------------------------
// proj = X @ W (fp32 accum), s_i = proj @ a[:64], s_j = proj @ a[64:]
// 512 blocks x 16 rows (R5-verified). Also publishes the f32 flag.
// ---------------------------------------------------------------------------
__global__ __launch_bounds__(256) void proj_kernel(
    const void* __restrict__ Xv, const void* __restrict__ Wv,
    const void* __restrict__ Av,
    float* __restrict__ proj, float* __restrict__ si, float* __restrict__ sj,
    int* __restrict__ gflags) {
    __shared__ unsigned short wL[IN_F * OUT_F];  // 32 KB
    __shared__ unsigned short xL[16 * IN_F];     // 8 KB
    __shared__ float aL[2 * OUT_F];
    __shared__ int sdet[2];

    int tid = threadIdx.x;
    if (tid == 0) { sdet[0] = 0; sdet[1] = 0; }
    __syncthreads();
    block_or(x_is_f32_local((const unsigned short*)Xv, tid), tid, sdet, 1);
    __syncthreads();
    bool xf32 = (sdet[1] != 0);
    if (tid == 0) gflags[1] = xf32 ? 1 : 0;   // all blocks write same value

    int row0 = blockIdx.x * 16;
    int tc = tid & 15;
    int r  = tid >> 4;
    int c0 = tc * 4;
    int row = row0 + r;

    float acc0 = 0.f, acc1 = 0.f, acc2 = 0.f, acc3 = 0.f;

    if (xf32) {
        const float* Xf = (const float*)Xv;
        const float* Wf = (const float*)Wv;
        const float* Af = (const float*)Av;
        if (tid < 2 * OUT_F) aL[tid] = Af[tid];
        __syncthreads();
        const float4* xr = (const float4*)(Xf + (size_t)row * IN_F);
#pragma unroll 2
        for (int kv = 0; kv < IN_F / 4; ++kv) {
            float4 xq = xr[kv];
#pragma unroll
            for (int t = 0; t < 4; ++t) {
                float x = (t == 0) ? xq.x : (t == 1) ? xq.y : (t == 2) ? xq.z : xq.w;
                float4 wq = *(const float4*)(Wf + (size_t)(kv * 4 + t) * OUT_F + c0);
                acc0 = fmaf(x, wq.x, acc0);
                acc1 = fmaf(x, wq.y, acc1);
                acc2 = fmaf(x, wq.z, acc2);
                acc3 = fmaf(x, wq.w, acc3);
            }
        }
    } else {
        const unsigned short* Xh = (const unsigned short*)Xv;
        const unsigned short* Wh = (const unsigned short*)Wv;
        const unsigned short* Ah = (const unsigned short*)Av;
        for (int i = tid; i < (IN_F * OUT_F) / 8; i += 256)
            ((uint4*)wL)[i] = ((const uint4*)Wh)[i];
        for (int i = tid; i < (16 * IN_F) / 8; i += 256)
            ((uint4*)xL)[i] = ((const uint4*)(Xh + (size_t)row0 * IN_F))[i];
        if (tid < 2 * OUT_F) aL[tid] = bf2f(Ah[tid]);
        __syncthreads();

        const uint4* xrv = (const uint4*)&xL[r * IN_F];
#pragma unroll 4
        for (int kv = 0; kv < IN_F / 8; ++kv) {
            uint4 xq = xrv[kv];
#pragma unroll
            for (int h = 0; h < 4; ++h) {
                unsigned int xp = (h == 0) ? xq.x : (h == 1) ? xq.y : (h == 2) ? xq.z : xq.w;
                int k0 = kv * 8 + h * 2;
                uint2 w0 = *(const uint2*)&wL[(k0 + 0) * OUT_F + c0];
                uint2 w1 = *(const uint2*)&wL[(k0 + 1) * OUT_F + c0];
                float xa = bflo(xp), xb = bfhi(xp);
                acc0 = fmaf(xa, bflo(w0.x), acc0);
                acc1 = fmaf(xa, bfhi(w0.x), acc1);
                acc2 = fmaf(xa, bflo(w0.y), acc2);
                acc3 = fmaf(xa, bfhi(w0.y), acc3);
                acc0 = fmaf(xb, bflo(w1.x), acc0);
                acc1 = fmaf(xb, bfhi(w1.x), acc1);
                acc2 = fmaf(xb, bflo(w1.y), acc2);
                acc3 = fmaf(xb, bfhi(w1.y), acc3);
            }
        }
    }

    *(float4*)&proj[(size_t)row * OUT_F + c0] = make_float4(acc0, acc1, acc2, acc3);

    float sa = acc0 * aL[c0] + acc1 * aL[c0 + 1] + acc2 * aL[c0 + 2] + acc3 * aL[c0 + 3];
    float sb = acc0 * aL[OUT_F + c0] + acc1 * aL[OUT_F + c0 + 1] +
               acc2 * aL[OUT_F + c0 + 2] + acc3 * aL[OUT_F + c0 + 3];
    for (int off = 8; off; off >>= 1) {
        sa += __shfl_xor(sa, off, 16);
        sb += __shfl_xor(sb, off, 16);
    }
    if (tc == 0) { si[row] = sa; sj[row] = sb; }
}

// ---------------------------------------------------------------------------
// Bitmask converter: one pure-stream pass over the adjacency (268 MB for
// int32) -> 8 MB bitmask. Per KB-chunk c: lane loads one uint4; ballots give
// u64 words bm[c*wpc + s], bit L = element of lane L. Element mapping (e =
// elems/lane/chunk = 4/8/16 for width 4/2/1):
//   word g (per row, 0..127), bit i:  j = 64*(g&~(e-1)) + (g&(e-1)) + e*i
// Also publishes the width flag.
// ---------------------------------------------------------------------------
__global__ __launch_bounds__(256, 8) void convert_kernel(
    const void* __restrict__ adj, unsigned long long* __restrict__ bm,
    int* __restrict__ gflags) {
    __shared__ int sdet[1];
    int tid = threadIdx.x, lane = tid & 63, wid = tid >> 6;
    if (tid == 0) sdet[0] = 0;
    __syncthreads();
    block_or(adj_viol_local((const unsigned int*)adj, tid), tid, sdet, 0);
    __syncthreads();
    int f = sdet[0];
    int width = (!(f & 1)) ? 4 : ((!(f & 2)) ? 2 : 1);
    if (tid == 0) gflags[0] = width;   // all blocks write same value

    int gw = blockIdx.x * 4 + wid;     // 8192 waves
    const uint4* p = (const uint4*)adj;

    if (width == 4) {
        // 262144 KB-chunks, 4 words each
        for (int cb = gw * 4; cb < 262144; cb += 32768) {
            uint4 v0 = p[(size_t)(cb + 0) * 64 + lane];
            uint4 v1 = p[(size_t)(cb + 1) * 64 + lane];
            uint4 v2 = p[(size_t)(cb + 2) * 64 + lane];
            uint4 v3 = p[(size_t)(cb + 3) * 64 + lane];
#pragma unroll
            for (int k = 0; k < 4; ++k) {
                uint4 v = (k == 0) ? v0 : (k == 1) ? v1 : (k == 2) ? v2 : v3;
                unsigned long long b0 = __ballot(v.x != 0u);
                unsigned long long b1 = __ballot(v.y != 0u);
                unsigned long long b2 = __ballot(v.z != 0u);
                unsigned long long b3 = __ballot(v.w != 0u);
                if (lane < 4) {
                    unsigned long long bb = (lane == 0) ? b0 : (lane == 1) ? b1
                                          : (lane == 2) ? b2 : b3;
                    bm[(size_t)(cb + k) * 4 + lane] = bb;
                }
            }
        }
    } else if (width == 2) {
        // 131072 KB-chunks, 8 words each (cold path for this harness)
        for (int cb = gw * 4; cb < 131072; cb += 32768) {
#pragma unroll
            for (int k = 0; k < 4; ++k) {
                int c = cb + k;
                uint4 v = p[(size_t)c * 64 + lane];
                unsigned long long b[8];
                b[0] = __ballot((v.x & 0xFFFFu) != 0u);
                b[1] = __ballot((v.x >> 16)     != 0u);
                b[2] = __ballot((v.y & 0xFFFFu) != 0u);
                b[3] = __ballot((v.y >> 16)     != 0u);
                b[4] = __ballot((v.z & 0xFFFFu) != 0u);
                b[5] = __ballot((v.z >> 16)     != 0u);
                b[6] = __ballot((v.w & 0xFFFFu) != 0u);
                b[7] = __ballot((v.w >> 16)     != 0u);
                if (lane == 0) {
#pragma unroll
                    for (int s = 0; s < 8; ++s) bm[(size_t)c * 8 + s] = b[s];
                }
            }
        }
    } else {
        // 65536 KB-chunks, 16 words each (cold path)
        for (int cb = gw * 4; cb < 65536; cb += 32768) {
#pragma unroll
            for (int k = 0; k < 4; ++k) {
                int c = cb + k;
                uint4 v = p[(size_t)c * 64 + lane];
                unsigned long long b[16];
#pragma unroll
                for (int h = 0; h < 4; ++h) {
                    unsigned int word = (h == 0) ? v.x : (h == 1) ? v.y : (h == 2) ? v.z : v.w;
                    b[4 * h + 0] = __ballot(((word)       & 0xFFu) != 0u);
                    b[4 * h + 1] = __ballot(((word >> 8)  & 0xFFu) != 0u);
                    b[4 * h + 2] = __ballot(((word >> 16) & 0xFFu) != 0u);
                    b[4 * h + 3] = __ballot(((word >> 24)        ) != 0u);
                }
                if (lane == 0) {
#pragma unroll
                    for (int s = 0; s < 16; ++s) bm[(size_t)c * 16 + s] = b[s];
                }
            }
        }
    }
}

// ---------------------------------------------------------------------------
// Fused masked softmax + h_out = attn @ proj. ONE ROW PER WAVE, driven by the
// 8 MB bitmask (1 KB/row): 2 u64 loads/lane, per-lane ctz over set bits,
// shuffle prefix-scan for compaction offsets (order-invariant softmax).
// Phases 2/3 identical to the R7-verified code.
// ---------------------------------------------------------------------------
__global__ __launch_bounds__(256, 8) void attn_kernel(
    const void* __restrict__ adj, const unsigned long long* __restrict__ bm,
    const int* __restrict__ gflags,
    const float* __restrict__ proj, const float* __restrict__ si_arr,
    const float* __restrict__ sj_arr, void* __restrict__ outv) {
    __shared__ int   s_idx[4 * CAP];   // 8 KB
    __shared__ float s_sc[4 * CAP];    // 8 KB

    int tid  = threadIdx.x;
    int lane = tid & 63;
    int wid  = tid >> 6;

    int width = gflags[0];
    bool f32o = (gflags[1] != 0);
    int e = (width == 4) ? 4 : (width == 2) ? 8 : 16;
    int emask = e - 1;

    int row = blockIdx.x * 4 + wid;
    int*   idxL = &s_idx[wid * CAP];
    float* scL  = &s_sc[wid * CAP];

    const unsigned long long* bmrow = bm + (size_t)row * 128;
    unsigned long long w0 = bmrow[lane];
    unsigned long long w1 = bmrow[64 + lane];
    int nb = __popcll(w0) + __popcll(w1);

    // inclusive shuffle scan -> exclusive offset + total
    int pos = nb;
    for (int o = 1; o < 64; o <<= 1) {
        int t = __shfl_up(pos, o, 64);
        if (lane >= o) pos += t;
    }
    int cnt = __shfl(pos, 63, 64);
    pos -= nb;

    // emit this lane's set bits into the compacted index list
    {
        int p = pos;
        int g = lane;
        unsigned long long w = w0;
        while (w) {
            int i = __builtin_ctzll(w); w &= w - 1;
            int j = ((g & ~emask) << 6) + (g & emask) + e * i;
            if (p < CAP) idxL[p] = j;
            ++p;
        }
        g = 64 + lane; w = w1;
        while (w) {
            int i = __builtin_ctzll(w); w &= w - 1;
            int j = ((g & ~emask) << 6) + (g & emask) + e * i;
            if (p < CAP) idxL[p] = j;
            ++p;
        }
    }

    float si = si_arr[row];

    if (cnt == 0) {
        // all-NEG_BIG row -> uniform softmax -> column mean of proj (never hit)
        float acc = 0.f;
#pragma unroll 4
        for (int j = 0; j < N_NODES; ++j) acc += proj[(size_t)j * OUT_F + lane];
        float h = acc * (1.0f / (float)N_NODES);
        if (f32o) ((float*)outv)[(size_t)row * OUT_F + lane] = h;
        else ((unsigned short*)outv)[(size_t)row * OUT_F + lane] = f2bf(h);
        return;
    }

    if (cnt <= CAP) {
        // phase 2: scores from compacted list
        float m = -3.0e38f;
        for (int k = lane; k < cnt; k += 64) {
            int j = idxL[k];
            float sc = si + sj_arr[j];
            sc = (sc >= 0.f) ? sc : NEG_SLOPE * sc;
            scL[k] = sc;
            m = fmaxf(m, sc);
        }
        for (int o = 32; o; o >>= 1) m = fmaxf(m, __shfl_xor(m, o, 64));

        float psum = 0.f;
        for (int k = lane; k < cnt; k += 64) {
            float w = expf(scL[k] - m);
            scL[k] = w;
            psum += w;
        }
        for (int o = 32; o; o >>= 1) psum += __shfl_xor(psum, o, 64);
        float inv_denom = 1.0f / psum;

        // phase 3: gather — lane = column; idxL/scL reads are LDS broadcasts
        float acc = 0.f;
#pragma unroll 4
        for (int k = 0; k < cnt; ++k)
            acc = fmaf(scL[k], proj[(size_t)idxL[k] * OUT_F + lane], acc);
        float h = acc * inv_denom;
        if (f32o) ((float*)outv)[(size_t)row * OUT_F + lane] = h;
        else ((unsigned short*)outv)[(size_t)row * OUT_F + lane] = f2bf(h);
        return;
    }

    // ---- overflow fallback (cnt > CAP): correct, slow, statistically never hit.
    float m = -3.0e38f;
#pragma unroll 1
    for (int j = lane; j < N_NODES; j += 64) {
        unsigned int mu;
        if (width == 4)      mu = ((const unsigned int*)adj)[(size_t)row * N_NODES + j];
        else if (width == 2) mu = ((const unsigned short*)adj)[(size_t)row * N_NODES + j];
        else                 mu = ((const unsigned char*)adj)[(size_t)row * N_NODES + j];
        if (mu) {
            float sc = si + sj_arr[j];
            sc = (sc >= 0.f) ? sc : NEG_SLOPE * sc;
            m = fmaxf(m, sc);
        }
    }
    for (int o = 32; o; o >>= 1) m = fmaxf(m, __shfl_xor(m, o, 64));
    float psum = 0.f;
#pragma unroll 1
    for (int j = lane; j < N_NODES; j += 64) {
        unsigned int mu;
        if (width == 4)      mu = ((const unsigned int*)adj)[(size_t)row * N_NODES + j];
        else if (width == 2) mu = ((const unsigned short*)adj)[(size_t)row * N_NODES + j];
        else                 mu = ((const unsigned char*)adj)[(size_t)row * N_NODES + j];
        if (mu) {
            float sc = si + sj_arr[j];
            sc = (sc >= 0.f) ? sc : NEG_SLOPE * sc;
            psum += expf(sc - m);
        }
    }
    for (int o = 32; o; o >>= 1) psum += __shfl_xor(psum, o, 64);
    float acc = 0.f;
#pragma unroll 1
    for (int j = 0; j < N_NODES; ++j) {
        unsigned int mu;
        if (width == 4)      mu = ((const unsigned int*)adj)[(size_t)row * N_NODES + j];
        else if (width == 2) mu = ((const unsigned short*)adj)[(size_t)row * N_NODES + j];
        else                 mu = ((const unsigned char*)adj)[(size_t)row * N_NODES + j];
        if (mu) {
            float sc = si + sj_arr[j];
            sc = (sc >= 0.f) ? sc : NEG_SLOPE * sc;
            acc = fmaf(expf(sc - m), proj[(size_t)j * OUT_F + lane], acc);
        }
    }
    float h = acc / psum;
    if (f32o) ((float*)outv)[(size_t)row * OUT_F + lane] = h;
    else ((unsigned short*)outv)[(size_t)row * OUT_F + lane] = f2bf(h);
}

extern "C" void kernel_launch(void* const* d_in, const int* in_sizes, int n_in,
                              void* d_out, int out_size, void* d_ws, size_t ws_size,
                              hipStream_t stream) {
    const void* X   = d_in[0];  // [8192,256] fp32 (runtime-detected; bf16 fallback)
    const void* adj = d_in[1];  // [8192,8192] bool as int32 (runtime-detected)
    const void* W   = d_in[2];  // [256,64]
    const void* A   = d_in[3];  // [128,1]

    char* ws = (char*)d_ws;
    float* si    = (float*)(ws + SI_OFF);
    float* sj    = (float*)(ws + SJ_OFF);
    float* proj  = (float*)(ws + PROJ_OFF);
    int*   gflag = (int*)(ws + FLAG_OFF);
    unsigned long long* bm = (unsigned long long*)(ws + BM_OFF);

    proj_kernel<<<N_NODES / 16, 256, 0, stream>>>(X, W, A, proj, si, sj, gflag);
    convert_kernel<<<2048, 256, 0, stream>>>(adj, bm, gflag);
    attn_kernel<<<2048, 256, 0, stream>>>(adj, bm, gflag, proj, si, sj, d_out);
}

// Round 9
// 395.390 us; speedup vs baseline: 1.0538x; 1.0538x over previous
//
#include <hip/hip_runtime.h>
#include <hip/hip_bf16.h>
#include <stdint.h>

#define N_NODES 8192
#define IN_F    256
#define OUT_F   64
#define NEG_SLOPE 0.2f
#define CAP     512       // per-wave neighbor list; mean degree 82, sd 9 -> 47 sigma
#define DET_WORDS  4096   // 16 KB adjacency prefix scanned per block (L2-cached)
#define DET_HALVES 8192   // 16 KB X prefix scanned per block

typedef unsigned int v4u __attribute__((ext_vector_type(4)));

// Non-temporal 16B load: nt bit -> avoid LLC allocation, so the harness's
// 256 MB of dirty ws-poison in L3 is not forcibly drained by our 268 MB
// adjacency stream (writeback-bill theory, R8 post-mortem).
static __device__ __forceinline__ v4u ntload(const v4u* p) {
    return __builtin_nontemporal_load(p);
}

static __device__ __forceinline__ float bf2f(unsigned short u) {
    union { unsigned int i; float f; } v; v.i = ((unsigned int)u) << 16; return v.f;
}
static __device__ __forceinline__ float bflo(unsigned int u) {
    union { unsigned int i; float f; } v; v.i = u << 16; return v.f;
}
static __device__ __forceinline__ float bfhi(unsigned int u) {
    union { unsigned int i; float f; } v; v.i = u & 0xFFFF0000u; return v.f;
}
static __device__ __forceinline__ unsigned short f2bf(float f) {
    union { float f; unsigned int i; } v; v.f = f;
    unsigned int x = v.i;
    unsigned int lsb = (x >> 16) & 1u;
    x += 0x7FFFu + lsb;
    return (unsigned short)(x >> 16);
}

// Adjacency width detection on shared 16KB prefix. bit0 = not 4-byte elems,
// bit1 = not 2-byte, bit2 = not 1-byte. (R5 FETCH=167MB => width 4 here.)
static __device__ __forceinline__ int adj_viol_local(const unsigned int* w, int tid) {
    int viol = 0;
    for (int i = tid; i < DET_WORDS; i += 256) {
        unsigned int v = w[i];
        if (v) {
            if (v != 1u && v != 0x3F800000u) viol |= 1;
            unsigned int h0 = v & 0xFFFFu, h1 = v >> 16;
            if ((h0 != 0u && h0 != 1u && h0 != 0x3F80u) ||
                (h1 != 0u && h1 != 1u && h1 != 0x3F80u)) viol |= 2;
            unsigned int b0 = v & 0xFFu, b1 = (v >> 8) & 0xFFu,
                         b2 = (v >> 16) & 0xFFu, b3 = v >> 24;
            if (b0 > 1u || b1 > 1u || b2 > 1u || b3 > 1u) viol |= 4;
        }
    }
    return viol;
}

// X dtype: nonzero => fp32 (bf16-exponent >= 133 occurs w.p. ~0.48 per fp32
// mantissa half, never in bf16 N(0,1)). R5-R8: fp32 for this harness.
static __device__ __forceinline__ int x_is_f32_local(const unsigned short* x, int tid) {
    int viol = 0;
    for (int i = tid; i < DET_HALVES; i += 256) {
        unsigned int e = ((unsigned int)x[i] >> 7) & 0xFFu;
        if (e >= 133u) viol = 1;
    }
    return viol;
}

static __device__ __forceinline__ void block_or(int v, int tid, int* sdet, int slot) {
    for (int o = 32; o; o >>= 1) v |= __shfl_xor(v, o, 64);
    if ((tid & 63) == 0 && v) atomicOr(&sdet[slot], v);
}

// ---------------------------------------------------------------------------
// proj = X @ W (fp32 accum), s_i = proj @ a[:64], s_j = proj @ a[64:]
// 512 blocks x 16 rows. Thread t: row=t>>4, cols (t&15)*4..+3. (R5-verified)
// ---------------------------------------------------------------------------
__global__ __launch_bounds__(256) void proj_kernel(
    const void* __restrict__ Xv, const void* __restrict__ Wv,
    const void* __restrict__ Av,
    float* __restrict__ proj, float* __restrict__ si, float* __restrict__ sj) {
    __shared__ unsigned short wL[IN_F * OUT_F];  // 32 KB
    __shared__ unsigned short xL[16 * IN_F];     // 8 KB
    __shared__ float aL[2 * OUT_F];
    __shared__ int sdet[2];

    int tid = threadIdx.x;
    if (tid == 0) { sdet[0] = 0; sdet[1] = 0; }
    __syncthreads();
    block_or(x_is_f32_local((const unsigned short*)Xv, tid), tid, sdet, 1);
    __syncthreads();
    bool xf32 = (sdet[1] != 0);

    int row0 = blockIdx.x * 16;
    int tc = tid & 15;
    int r  = tid >> 4;
    int c0 = tc * 4;
    int row = row0 + r;

    float acc0 = 0.f, acc1 = 0.f, acc2 = 0.f, acc3 = 0.f;

    if (xf32) {
        const float* Xf = (const float*)Xv;
        const float* Wf = (const float*)Wv;
        const float* Af = (const float*)Av;
        if (tid < 2 * OUT_F) aL[tid] = Af[tid];
        __syncthreads();
        const float4* xr = (const float4*)(Xf + (size_t)row * IN_F);
#pragma unroll 2
        for (int kv = 0; kv < IN_F / 4; ++kv) {
            float4 xq = xr[kv];
#pragma unroll
            for (int t = 0; t < 4; ++t) {
                float x = (t == 0) ? xq.x : (t == 1) ? xq.y : (t == 2) ? xq.z : xq.w;
                float4 wq = *(const float4*)(Wf + (size_t)(kv * 4 + t) * OUT_F + c0);
                acc0 = fmaf(x, wq.x, acc0);
                acc1 = fmaf(x, wq.y, acc1);
                acc2 = fmaf(x, wq.z, acc2);
                acc3 = fmaf(x, wq.w, acc3);
            }
        }
    } else {
        const unsigned short* Xh = (const unsigned short*)Xv;
        const unsigned short* Wh = (const unsigned short*)Wv;
        const unsigned short* Ah = (const unsigned short*)Av;
        for (int i = tid; i < (IN_F * OUT_F) / 8; i += 256)
            ((uint4*)wL)[i] = ((const uint4*)Wh)[i];
        for (int i = tid; i < (16 * IN_F) / 8; i += 256)
            ((uint4*)xL)[i] = ((const uint4*)(Xh + (size_t)row0 * IN_F))[i];
        if (tid < 2 * OUT_F) aL[tid] = bf2f(Ah[tid]);
        __syncthreads();

        const uint4* xrv = (const uint4*)&xL[r * IN_F];
#pragma unroll 4
        for (int kv = 0; kv < IN_F / 8; ++kv) {
            uint4 xq = xrv[kv];
#pragma unroll
            for (int h = 0; h < 4; ++h) {
                unsigned int xp = (h == 0) ? xq.x : (h == 1) ? xq.y : (h == 2) ? xq.z : xq.w;
                int k0 = kv * 8 + h * 2;
                uint2 w0 = *(const uint2*)&wL[(k0 + 0) * OUT_F + c0];
                uint2 w1 = *(const uint2*)&wL[(k0 + 1) * OUT_F + c0];
                float xa = bflo(xp), xb = bfhi(xp);
                acc0 = fmaf(xa, bflo(w0.x), acc0);
                acc1 = fmaf(xa, bfhi(w0.x), acc1);
                acc2 = fmaf(xa, bflo(w0.y), acc2);
                acc3 = fmaf(xa, bfhi(w0.y), acc3);
                acc0 = fmaf(xb, bflo(w1.x), acc0);
                acc1 = fmaf(xb, bfhi(w1.x), acc1);
                acc2 = fmaf(xb, bflo(w1.y), acc2);
                acc3 = fmaf(xb, bfhi(w1.y), acc3);
            }
        }
    }

    *(float4*)&proj[(size_t)row * OUT_F + c0] = make_float4(acc0, acc1, acc2, acc3);

    float sa = acc0 * aL[c0] + acc1 * aL[c0 + 1] + acc2 * aL[c0 + 2] + acc3 * aL[c0 + 3];
    float sb = acc0 * aL[OUT_F + c0] + acc1 * aL[OUT_F + c0 + 1] +
               acc2 * aL[OUT_F + c0 + 2] + acc3 * aL[OUT_F + c0 + 3];
    for (int off = 8; off; off >>= 1) {
        sa += __shfl_xor(sa, off, 16);
        sb += __shfl_xor(sb, off, 16);
    }
    if (tc == 0) { si[row] = sa; sj[row] = sb; }
}

// Index-only ballot compaction: no global loads, no score math in the scan.
static __device__ __forceinline__ void compact_idx(
    bool hit, int j, int lane, unsigned long long mask_lt,
    int& base, int* __restrict__ idxL) {
    unsigned long long b = __ballot(hit);
    if (hit) {
        int pos = base + (int)__popcll(b & mask_lt);
        if (pos < CAP) idxL[pos] = j;
    }
    base += (int)__popcll(b);
}

// ---------------------------------------------------------------------------
// Fused masked softmax + h_out = attn @ proj. ONE ROW PER WAVE (R7-verified).
// Adjacency stream uses NON-TEMPORAL loads to avoid forcing L3 dirty-line
// writebacks of harness ws-poison. 2048 blocks x 4 waves; 8 blocks/CU.
// ---------------------------------------------------------------------------
__global__ __launch_bounds__(256, 8) void attn_kernel(
    const void* __restrict__ adj, const void* __restrict__ Xv,
    const float* __restrict__ proj, const float* __restrict__ si_arr,
    const float* __restrict__ sj_arr, void* __restrict__ outv) {
    __shared__ int   s_idx[4 * CAP];   // 8 KB (2 KB per wave)
    __shared__ float s_sc[4 * CAP];    // 8 KB (2 KB per wave)
    __shared__ int   sdet[2];

    int tid  = threadIdx.x;
    int lane = tid & 63;
    int wid  = tid >> 6;

    if (tid == 0) { sdet[0] = 0; sdet[1] = 0; }
    __syncthreads();
    block_or(adj_viol_local((const unsigned int*)adj, tid), tid, sdet, 0);
    block_or(x_is_f32_local((const unsigned short*)Xv, tid), tid, sdet, 1);
    __syncthreads();
    int f = sdet[0];
    int width = (!(f & 1)) ? 4 : ((!(f & 2)) ? 2 : 1);
    bool f32o = (sdet[1] != 0);

    int row = blockIdx.x * 4 + wid;
    int*   idxL = &s_idx[wid * CAP];
    float* scL  = &s_sc[wid * CAP];

    unsigned long long mask_lt = (1ull << lane) - 1ull;
    float si = si_arr[row];
    int base = 0;   // wave-uniform neighbor count

    if (width == 4) {
        const v4u* p = (const v4u*)((const unsigned int*)adj + (size_t)row * N_NODES);
        v4u c0 = ntload(p + lane), c1 = ntload(p + lane + 64),
            c2 = ntload(p + lane + 128), c3 = ntload(p + lane + 192);
#pragma unroll 1
        for (int it = 0; it < 8; ++it) {
            v4u n0, n1, n2, n3;
            if (it < 7) {
                int v = (it + 1) * 256 + lane;
                n0 = ntload(p + v); n1 = ntload(p + v + 64);
                n2 = ntload(p + v + 128); n3 = ntload(p + v + 192);
            }
#pragma unroll
            for (int q = 0; q < 4; ++q) {
                v4u c = (q == 0) ? c0 : (q == 1) ? c1 : (q == 2) ? c2 : c3;
                int j0 = 4 * (it * 256 + lane + q * 64);
                compact_idx(c.x != 0u, j0 + 0, lane, mask_lt, base, idxL);
                compact_idx(c.y != 0u, j0 + 1, lane, mask_lt, base, idxL);
                compact_idx(c.z != 0u, j0 + 2, lane, mask_lt, base, idxL);
                compact_idx(c.w != 0u, j0 + 3, lane, mask_lt, base, idxL);
            }
            c0 = n0; c1 = n1; c2 = n2; c3 = n3;
        }
    } else if (width == 2) {
        const v4u* p = (const v4u*)((const unsigned short*)adj + (size_t)row * N_NODES);
#pragma unroll 1
        for (int it = 0; it < 4; ++it) {
            int v0 = it * 256 + lane;
            v4u c0 = ntload(p + v0), c1 = ntload(p + v0 + 64),
                c2 = ntload(p + v0 + 128), c3 = ntload(p + v0 + 192);
#pragma unroll
            for (int q = 0; q < 4; ++q) {
                v4u c = (q == 0) ? c0 : (q == 1) ? c1 : (q == 2) ? c2 : c3;
                int j0 = 8 * (v0 + q * 64);
#pragma unroll
                for (int h = 0; h < 4; ++h) {
                    unsigned int word = (h == 0) ? c.x : (h == 1) ? c.y : (h == 2) ? c.z : c.w;
                    compact_idx((word & 0xFFFFu) != 0u, j0 + 2 * h + 0, lane, mask_lt, base, idxL);
                    compact_idx((word >> 16)     != 0u, j0 + 2 * h + 1, lane, mask_lt, base, idxL);
                }
            }
        }
    } else {
        const v4u* p = (const v4u*)((const unsigned char*)adj + (size_t)row * N_NODES);
#pragma unroll 1
        for (int it = 0; it < 2; ++it) {
            int v0 = it * 256 + lane;
            v4u c0 = ntload(p + v0), c1 = ntload(p + v0 + 64),
                c2 = ntload(p + v0 + 128), c3 = ntload(p + v0 + 192);
#pragma unroll
            for (int q = 0; q < 4; ++q) {
                v4u c = (q == 0) ? c0 : (q == 1) ? c1 : (q == 2) ? c2 : c3;
                int j0 = 16 * (v0 + q * 64);
#pragma unroll
                for (int h = 0; h < 4; ++h) {
                    unsigned int word = (h == 0) ? c.x : (h == 1) ? c.y : (h == 2) ? c.z : c.w;
                    compact_idx(((word)       & 0xFFu) != 0u, j0 + 4 * h + 0, lane, mask_lt, base, idxL);
                    compact_idx(((word >> 8)  & 0xFFu) != 0u, j0 + 4 * h + 1, lane, mask_lt, base, idxL);
                    compact_idx(((word >> 16) & 0xFFu) != 0u, j0 + 4 * h + 2, lane, mask_lt, base, idxL);
                    compact_idx(((word >> 24)        ) != 0u, j0 + 4 * h + 3, lane, mask_lt, base, idxL);
                }
            }
        }
    }

    int cnt = base;

    if (cnt == 0) {
        // all-NEG_BIG row -> uniform softmax -> column mean of proj (never hit)
        float acc = 0.f;
#pragma unroll 4
        for (int j = 0; j < N_NODES; ++j) acc += proj[(size_t)j * OUT_F + lane];
        float h = acc * (1.0f / (float)N_NODES);
        if (f32o) ((float*)outv)[(size_t)row * OUT_F + lane] = h;
        else ((unsigned short*)outv)[(size_t)row * OUT_F + lane] = f2bf(h);
        return;
    }

    if (cnt <= CAP) {
        // phase 2: scores from compacted list — <=2 parallel sj gathers/lane
        float m = -3.0e38f;
        for (int k = lane; k < cnt; k += 64) {
            int j = idxL[k];
            float sc = si + sj_arr[j];
            sc = (sc >= 0.f) ? sc : NEG_SLOPE * sc;
            scL[k] = sc;
            m = fmaxf(m, sc);
        }
        for (int o = 32; o; o >>= 1) m = fmaxf(m, __shfl_xor(m, o, 64));

        float psum = 0.f;
        for (int k = lane; k < cnt; k += 64) {
            float w = expf(scL[k] - m);
            scL[k] = w;
            psum += w;
        }
        for (int o = 32; o; o >>= 1) psum += __shfl_xor(psum, o, 64);
        float inv_denom = 1.0f / psum;

        // phase 3: gather — lane = column; idxL/scL reads are LDS broadcasts
        float acc = 0.f;
#pragma unroll 4
        for (int k = 0; k < cnt; ++k)
            acc = fmaf(scL[k], proj[(size_t)idxL[k] * OUT_F + lane], acc);
        float h = acc * inv_denom;
        if (f32o) ((float*)outv)[(size_t)row * OUT_F + lane] = h;
        else ((unsigned short*)outv)[(size_t)row * OUT_F + lane] = f2bf(h);
        return;
    }

    // ---- overflow fallback (cnt > CAP): correct, slow, statistically never hit.
    float m = -3.0e38f;
#pragma unroll 1
    for (int j = lane; j < N_NODES; j += 64) {
        unsigned int mu;
        if (width == 4)      mu = ((const unsigned int*)adj)[(size_t)row * N_NODES + j];
        else if (width == 2) mu = ((const unsigned short*)adj)[(size_t)row * N_NODES + j];
        else                 mu = ((const unsigned char*)adj)[(size_t)row * N_NODES + j];
        if (mu) {
            float sc = si + sj_arr[j];
            sc = (sc >= 0.f) ? sc : NEG_SLOPE * sc;
            m = fmaxf(m, sc);
        }
    }
    for (int o = 32; o; o >>= 1) m = fmaxf(m, __shfl_xor(m, o, 64));
    float psum = 0.f;
#pragma unroll 1
    for (int j = lane; j < N_NODES; j += 64) {
        unsigned int mu;
        if (width == 4)      mu = ((const unsigned int*)adj)[(size_t)row * N_NODES + j];
        else if (width == 2) mu = ((const unsigned short*)adj)[(size_t)row * N_NODES + j];
        else                 mu = ((const unsigned char*)adj)[(size_t)row * N_NODES + j];
        if (mu) {
            float sc = si + sj_arr[j];
            sc = (sc >= 0.f) ? sc : NEG_SLOPE * sc;
            psum += expf(sc - m);
        }
    }
    for (int o = 32; o; o >>= 1) psum += __shfl_xor(psum, o, 64);
    float acc = 0.f;
#pragma unroll 1
    for (int j = 0; j < N_NODES; ++j) {
        unsigned int mu;
        if (width == 4)      mu = ((const unsigned int*)adj)[(size_t)row * N_NODES + j];
        else if (width == 2) mu = ((const unsigned short*)adj)[(size_t)row * N_NODES + j];
        else                 mu = ((const unsigned char*)adj)[(size_t)row * N_NODES + j];
        if (mu) {
            float sc = si + sj_arr[j];
            sc = (sc >= 0.f) ? sc : NEG_SLOPE * sc;
            acc = fmaf(expf(sc - m), proj[(size_t)j * OUT_F + lane], acc);
        }
    }
    float h = acc / psum;
    if (f32o) ((float*)outv)[(size_t)row * OUT_F + lane] = h;
    else ((unsigned short*)outv)[(size_t)row * OUT_F + lane] = f2bf(h);
}

extern "C" void kernel_launch(void* const* d_in, const int* in_sizes, int n_in,
                              void* d_out, int out_size, void* d_ws, size_t ws_size,
                              hipStream_t stream) {
    const void* X   = d_in[0];  // [8192,256] fp32 (runtime-detected; bf16 fallback)
    const void* adj = d_in[1];  // [8192,8192] bool as int32 (runtime-detected)
    const void* W   = d_in[2];  // [256,64]
    const void* A   = d_in[3];  // [128,1]

    char* ws = (char*)d_ws;
    float* si   = (float*)ws;
    float* sj   = (float*)(ws + 32768);
    float* proj = (float*)(ws + 65536);

    proj_kernel<<<N_NODES / 16, 256, 0, stream>>>(X, W, A, proj, si, sj);
    attn_kernel<<<N_NODES / 4, 256, 0, stream>>>(adj, X, proj, si, sj, d_out);
}

// Round 10
// 379.951 us; speedup vs baseline: 1.0967x; 1.0406x over previous
//
#include <hip/hip_runtime.h>
#include <hip/hip_bf16.h>
#include <stdint.h>

#define N_NODES 8192
#define IN_F    256
#define OUT_F   64
#define NEG_SLOPE 0.2f
#define CAP     512       // per-wave neighbor list; mean degree 82, sd 9 -> 47 sigma

typedef unsigned int v4u __attribute__((ext_vector_type(4)));

// Non-temporal 16B load (R9: -15us on the adjacency stream).
static __device__ __forceinline__ v4u ntload(const v4u* p) {
    return __builtin_nontemporal_load(p);
}

static __device__ __forceinline__ float bf2f(unsigned short u) {
    union { unsigned int i; float f; } v; v.i = ((unsigned int)u) << 16; return v.f;
}
static __device__ __forceinline__ float bflo(unsigned int u) {
    union { unsigned int i; float f; } v; v.i = u << 16; return v.f;
}
static __device__ __forceinline__ float bfhi(unsigned int u) {
    union { unsigned int i; float f; } v; v.i = u & 0xFFFF0000u; return v.f;
}
static __device__ __forceinline__ unsigned short f2bf(float f) {
    union { float f; unsigned int i; } v; v.f = f;
    unsigned int x = v.i;
    unsigned int lsb = (x >> 16) & 1u;
    x += 0x7FFFu + lsb;
    return (unsigned short)(x >> 16);
}

// ---------------------------------------------------------------------------
// ONE-SHOT dtype detection (hoisted out of the hot kernels — R9 post-mortem:
// per-block rolled detect loops were ~10us latency chains at the head of all
// 2048 attn blocks). 8 blocks scan disjoint 16KB segments with batched uint4
// loads (one waitcnt), atomicOr violations into gflags.
//   gflags[0]: adj violations — bit0 = not 4-byte elems (words in
//              {0,1,0x3F800000}), bit1 = not 2-byte, bit2 = not 1-byte.
//              width = 4 if !bit0 else 2 if !bit1 else 1.
//   gflags[1]: nonzero => X is fp32 (bf16-exponent >= 133 occurs w.p. ~.48
//              per fp32 mantissa half, never in bf16 N(0,1) data).
// gflags zeroed by hipMemsetAsync before launch.  R5-R9: width=4, fp32.
// ---------------------------------------------------------------------------
__global__ __launch_bounds__(256) void detect_kernel(
    const unsigned int* __restrict__ adj, const unsigned short* __restrict__ x,
    int* __restrict__ gflags) {
    int tid = threadIdx.x;
    int blk = blockIdx.x;

    // ---- adjacency: this block's 16KB segment, 4 independent uint4/thread
    const v4u* pa = (const v4u*)(adj + (size_t)blk * 4096);
    v4u a0 = pa[tid], a1 = pa[tid + 256], a2 = pa[tid + 512], a3 = pa[tid + 768];
    // ---- X: this block's 16KB segment, 4 independent uint4/thread
    const v4u* px = (const v4u*)(x + (size_t)blk * 8192);
    v4u x0 = px[tid], x1 = px[tid + 256], x2 = px[tid + 512], x3 = px[tid + 768];

    int viol = 0;
#pragma unroll
    for (int k = 0; k < 4; ++k) {
        v4u a = (k == 0) ? a0 : (k == 1) ? a1 : (k == 2) ? a2 : a3;
#pragma unroll
        for (int h = 0; h < 4; ++h) {
            unsigned int v = (h == 0) ? a.x : (h == 1) ? a.y : (h == 2) ? a.z : a.w;
            if (v) {
                if (v != 1u && v != 0x3F800000u) viol |= 1;
                unsigned int h0 = v & 0xFFFFu, h1 = v >> 16;
                if ((h0 != 0u && h0 != 1u && h0 != 0x3F80u) ||
                    (h1 != 0u && h1 != 1u && h1 != 0x3F80u)) viol |= 2;
                unsigned int b0 = v & 0xFFu, b1 = (v >> 8) & 0xFFu,
                             b2 = (v >> 16) & 0xFFu, b3 = v >> 24;
                if (b0 > 1u || b1 > 1u || b2 > 1u || b3 > 1u) viol |= 4;
            }
        }
    }
    int xf = 0;
#pragma unroll
    for (int k = 0; k < 4; ++k) {
        v4u a = (k == 0) ? x0 : (k == 1) ? x1 : (k == 2) ? x2 : x3;
#pragma unroll
        for (int h = 0; h < 4; ++h) {
            unsigned int v = (h == 0) ? a.x : (h == 1) ? a.y : (h == 2) ? a.z : a.w;
            unsigned int e0 = (v >> 7) & 0xFFu, e1 = (v >> 23) & 0xFFu;
            if (e0 >= 133u || e1 >= 133u) xf = 1;
        }
    }
    for (int o = 32; o; o >>= 1) {
        viol |= __shfl_xor(viol, o, 64);
        xf   |= __shfl_xor(xf, o, 64);
    }
    if ((tid & 63) == 0) {
        if (viol) atomicOr(&gflags[0], viol);
        if (xf)   atomicOr(&gflags[1], 1);
    }
}

// ---------------------------------------------------------------------------
// proj = X @ W (fp32 accum), s_i = proj @ a[:64], s_j = proj @ a[64:]
// 512 blocks x 16 rows. Thread t: row=t>>4, cols (t&15)*4..+3. (R5-verified)
// ---------------------------------------------------------------------------
__global__ __launch_bounds__(256) void proj_kernel(
    const void* __restrict__ Xv, const void* __restrict__ Wv,
    const void* __restrict__ Av, const int* __restrict__ gflags,
    float* __restrict__ proj, float* __restrict__ si, float* __restrict__ sj) {
    __shared__ unsigned short wL[IN_F * OUT_F];  // 32 KB
    __shared__ unsigned short xL[16 * IN_F];     // 8 KB
    __shared__ float aL[2 * OUT_F];

    int tid = threadIdx.x;
    bool xf32 = (gflags[1] != 0);

    int row0 = blockIdx.x * 16;
    int tc = tid & 15;
    int r  = tid >> 4;
    int c0 = tc * 4;
    int row = row0 + r;

    float acc0 = 0.f, acc1 = 0.f, acc2 = 0.f, acc3 = 0.f;

    if (xf32) {
        const float* Xf = (const float*)Xv;
        const float* Wf = (const float*)Wv;
        const float* Af = (const float*)Av;
        if (tid < 2 * OUT_F) aL[tid] = Af[tid];
        __syncthreads();
        const float4* xr = (const float4*)(Xf + (size_t)row * IN_F);
#pragma unroll 2
        for (int kv = 0; kv < IN_F / 4; ++kv) {
            float4 xq = xr[kv];
#pragma unroll
            for (int t = 0; t < 4; ++t) {
                float x = (t == 0) ? xq.x : (t == 1) ? xq.y : (t == 2) ? xq.z : xq.w;
                float4 wq = *(const float4*)(Wf + (size_t)(kv * 4 + t) * OUT_F + c0);
                acc0 = fmaf(x, wq.x, acc0);
                acc1 = fmaf(x, wq.y, acc1);
                acc2 = fmaf(x, wq.z, acc2);
                acc3 = fmaf(x, wq.w, acc3);
            }
        }
    } else {
        const unsigned short* Xh = (const unsigned short*)Xv;
        const unsigned short* Wh = (const unsigned short*)Wv;
        const unsigned short* Ah = (const unsigned short*)Av;
        for (int i = tid; i < (IN_F * OUT_F) / 8; i += 256)
            ((uint4*)wL)[i] = ((const uint4*)Wh)[i];
        for (int i = tid; i < (16 * IN_F) / 8; i += 256)
            ((uint4*)xL)[i] = ((const uint4*)(Xh + (size_t)row0 * IN_F))[i];
        if (tid < 2 * OUT_F) aL[tid] = bf2f(Ah[tid]);
        __syncthreads();

        const uint4* xrv = (const uint4*)&xL[r * IN_F];
#pragma unroll 4
        for (int kv = 0; kv < IN_F / 8; ++kv) {
            uint4 xq = xrv[kv];
#pragma unroll
            for (int h = 0; h < 4; ++h) {
                unsigned int xp = (h == 0) ? xq.x : (h == 1) ? xq.y : (h == 2) ? xq.z : xq.w;
                int k0 = kv * 8 + h * 2;
                uint2 w0 = *(const uint2*)&wL[(k0 + 0) * OUT_F + c0];
                uint2 w1 = *(const uint2*)&wL[(k0 + 1) * OUT_F + c0];
                float xa = bflo(xp), xb = bfhi(xp);
                acc0 = fmaf(xa, bflo(w0.x), acc0);
                acc1 = fmaf(xa, bfhi(w0.x), acc1);
                acc2 = fmaf(xa, bflo(w0.y), acc2);
                acc3 = fmaf(xa, bfhi(w0.y), acc3);
                acc0 = fmaf(xb, bflo(w1.x), acc0);
                acc1 = fmaf(xb, bfhi(w1.x), acc1);
                acc2 = fmaf(xb, bflo(w1.y), acc2);
                acc3 = fmaf(xb, bfhi(w1.y), acc3);
            }
        }
    }

    *(float4*)&proj[(size_t)row * OUT_F + c0] = make_float4(acc0, acc1, acc2, acc3);

    float sa = acc0 * aL[c0] + acc1 * aL[c0 + 1] + acc2 * aL[c0 + 2] + acc3 * aL[c0 + 3];
    float sb = acc0 * aL[OUT_F + c0] + acc1 * aL[OUT_F + c0 + 1] +
               acc2 * aL[OUT_F + c0 + 2] + acc3 * aL[OUT_F + c0 + 3];
    for (int off = 8; off; off >>= 1) {
        sa += __shfl_xor(sa, off, 16);
        sb += __shfl_xor(sb, off, 16);
    }
    if (tc == 0) { si[row] = sa; sj[row] = sb; }
}

// Index-only ballot compaction: no global loads, no score math in the scan.
static __device__ __forceinline__ void compact_idx(
    bool hit, int j, int lane, unsigned long long mask_lt,
    int& base, int* __restrict__ idxL) {
    unsigned long long b = __ballot(hit);
    if (hit) {
        int pos = base + (int)__popcll(b & mask_lt);
        if (pos < CAP) idxL[pos] = j;
    }
    base += (int)__popcll(b);
}

// ---------------------------------------------------------------------------
// Fused masked softmax + h_out = attn @ proj. ONE ROW PER WAVE, nt loads,
// NO per-block detection (reads gflags). 2048 blocks x 4 waves; 8 blocks/CU.
// ---------------------------------------------------------------------------
__global__ __launch_bounds__(256, 8) void attn_kernel(
    const void* __restrict__ adj, const int* __restrict__ gflags,
    const float* __restrict__ proj, const float* __restrict__ si_arr,
    const float* __restrict__ sj_arr, void* __restrict__ outv) {
    __shared__ int   s_idx[4 * CAP];   // 8 KB (2 KB per wave)
    __shared__ float s_sc[4 * CAP];    // 8 KB (2 KB per wave)

    int tid  = threadIdx.x;
    int lane = tid & 63;
    int wid  = tid >> 6;

    int f = gflags[0];
    int width = (!(f & 1)) ? 4 : ((!(f & 2)) ? 2 : 1);
    bool f32o = (gflags[1] != 0);

    int row = blockIdx.x * 4 + wid;
    int*   idxL = &s_idx[wid * CAP];
    float* scL  = &s_sc[wid * CAP];

    unsigned long long mask_lt = (1ull << lane) - 1ull;
    float si = si_arr[row];
    int base = 0;   // wave-uniform neighbor count

    if (width == 4) {
        const v4u* p = (const v4u*)((const unsigned int*)adj + (size_t)row * N_NODES);
        v4u c0 = ntload(p + lane), c1 = ntload(p + lane + 64),
            c2 = ntload(p + lane + 128), c3 = ntload(p + lane + 192);
#pragma unroll 1
        for (int it = 0; it < 8; ++it) {
            v4u n0, n1, n2, n3;
            if (it < 7) {
                int v = (it + 1) * 256 + lane;
                n0 = ntload(p + v); n1 = ntload(p + v + 64);
                n2 = ntload(p + v + 128); n3 = ntload(p + v + 192);
            }
#pragma unroll
            for (int q = 0; q < 4; ++q) {
                v4u c = (q == 0) ? c0 : (q == 1) ? c1 : (q == 2) ? c2 : c3;
                int j0 = 4 * (it * 256 + lane + q * 64);
                compact_idx(c.x != 0u, j0 + 0, lane, mask_lt, base, idxL);
                compact_idx(c.y != 0u, j0 + 1, lane, mask_lt, base, idxL);
                compact_idx(c.z != 0u, j0 + 2, lane, mask_lt, base, idxL);
                compact_idx(c.w != 0u, j0 + 3, lane, mask_lt, base, idxL);
            }
            c0 = n0; c1 = n1; c2 = n2; c3 = n3;
        }
    } else if (width == 2) {
        const v4u* p = (const v4u*)((const unsigned short*)adj + (size_t)row * N_NODES);
#pragma unroll 1
        for (int it = 0; it < 4; ++it) {
            int v0 = it * 256 + lane;
            v4u c0 = ntload(p + v0), c1 = ntload(p + v0 + 64),
                c2 = ntload(p + v0 + 128), c3 = ntload(p + v0 + 192);
#pragma unroll
            for (int q = 0; q < 4; ++q) {
                v4u c = (q == 0) ? c0 : (q == 1) ? c1 : (q == 2) ? c2 : c3;
                int j0 = 8 * (v0 + q * 64);
#pragma unroll
                for (int h = 0; h < 4; ++h) {
                    unsigned int word = (h == 0) ? c.x : (h == 1) ? c.y : (h == 2) ? c.z : c.w;
                    compact_idx((word & 0xFFFFu) != 0u, j0 + 2 * h + 0, lane, mask_lt, base, idxL);
                    compact_idx((word >> 16)     != 0u, j0 + 2 * h + 1, lane, mask_lt, base, idxL);
                }
            }
        }
    } else {
        const v4u* p = (const v4u*)((const unsigned char*)adj + (size_t)row * N_NODES);
#pragma unroll 1
        for (int it = 0; it < 2; ++it) {
            int v0 = it * 256 + lane;
            v4u c0 = ntload(p + v0), c1 = ntload(p + v0 + 64),
                c2 = ntload(p + v0 + 128), c3 = ntload(p + v0 + 192);
#pragma unroll
            for (int q = 0; q < 4; ++q) {
                v4u c = (q == 0) ? c0 : (q == 1) ? c1 : (q == 2) ? c2 : c3;
                int j0 = 16 * (v0 + q * 64);
#pragma unroll
                for (int h = 0; h < 4; ++h) {
                    unsigned int word = (h == 0) ? c.x : (h == 1) ? c.y : (h == 2) ? c.z : c.w;
                    compact_idx(((word)       & 0xFFu) != 0u, j0 + 4 * h + 0, lane, mask_lt, base, idxL);
                    compact_idx(((word >> 8)  & 0xFFu) != 0u, j0 + 4 * h + 1, lane, mask_lt, base, idxL);
                    compact_idx(((word >> 16) & 0xFFu) != 0u, j0 + 4 * h + 2, lane, mask_lt, base, idxL);
                    compact_idx(((word >> 24)        ) != 0u, j0 + 4 * h + 3, lane, mask_lt, base, idxL);
                }
            }
        }
    }

    int cnt = base;

    if (cnt == 0) {
        // all-NEG_BIG row -> uniform softmax -> column mean of proj (never hit)
        float acc = 0.f;
#pragma unroll 4
        for (int j = 0; j < N_NODES; ++j) acc += proj[(size_t)j * OUT_F + lane];
        float h = acc * (1.0f / (float)N_NODES);
        if (f32o) ((float*)outv)[(size_t)row * OUT_F + lane] = h;
        else ((unsigned short*)outv)[(size_t)row * OUT_F + lane] = f2bf(h);
        return;
    }

    if (cnt <= CAP) {
        // phase 2: scores from compacted list — <=2 parallel sj gathers/lane
        float m = -3.0e38f;
        for (int k = lane; k < cnt; k += 64) {
            int j = idxL[k];
            float sc = si + sj_arr[j];
            sc = (sc >= 0.f) ? sc : NEG_SLOPE * sc;
            scL[k] = sc;
            m = fmaxf(m, sc);
        }
        for (int o = 32; o; o >>= 1) m = fmaxf(m, __shfl_xor(m, o, 64));

        float psum = 0.f;
        for (int k = lane; k < cnt; k += 64) {
            float w = expf(scL[k] - m);
            scL[k] = w;
            psum += w;
        }
        for (int o = 32; o; o >>= 1) psum += __shfl_xor(psum, o, 64);
        float inv_denom = 1.0f / psum;

        // phase 3: gather — lane = column; idxL/scL reads are LDS broadcasts
        float acc = 0.f;
#pragma unroll 4
        for (int k = 0; k < cnt; ++k)
            acc = fmaf(scL[k], proj[(size_t)idxL[k] * OUT_F + lane], acc);
        float h = acc * inv_denom;
        if (f32o) ((float*)outv)[(size_t)row * OUT_F + lane] = h;
        else ((unsigned short*)outv)[(size_t)row * OUT_F + lane] = f2bf(h);
        return;
    }

    // ---- overflow fallback (cnt > CAP): correct, slow, statistically never hit.
    float m = -3.0e38f;
#pragma unroll 1
    for (int j = lane; j < N_NODES; j += 64) {
        unsigned int mu;
        if (width == 4)      mu = ((const unsigned int*)adj)[(size_t)row * N_NODES + j];
        else if (width == 2) mu = ((const unsigned short*)adj)[(size_t)row * N_NODES + j];
        else                 mu = ((const unsigned char*)adj)[(size_t)row * N_NODES + j];
        if (mu) {
            float sc = si + sj_arr[j];
            sc = (sc >= 0.f) ? sc : NEG_SLOPE * sc;
            m = fmaxf(m, sc);
        }
    }
    for (int o = 32; o; o >>= 1) m = fmaxf(m, __shfl_xor(m, o, 64));
    float psum = 0.f;
#pragma unroll 1
    for (int j = lane; j < N_NODES; j += 64) {
        unsigned int mu;
        if (width == 4)      mu = ((const unsigned int*)adj)[(size_t)row * N_NODES + j];
        else if (width == 2) mu = ((const unsigned short*)adj)[(size_t)row * N_NODES + j];
        else                 mu = ((const unsigned char*)adj)[(size_t)row * N_NODES + j];
        if (mu) {
            float sc = si + sj_arr[j];
            sc = (sc >= 0.f) ? sc : NEG_SLOPE * sc;
            psum += expf(sc - m);
        }
    }
    for (int o = 32; o; o >>= 1) psum += __shfl_xor(psum, o, 64);
    float acc = 0.f;
#pragma unroll 1
    for (int j = 0; j < N_NODES; ++j) {
        unsigned int mu;
        if (width == 4)      mu = ((const unsigned int*)adj)[(size_t)row * N_NODES + j];
        else if (width == 2) mu = ((const unsigned short*)adj)[(size_t)row * N_NODES + j];
        else                 mu = ((const unsigned char*)adj)[(size_t)row * N_NODES + j];
        if (mu) {
            float sc = si + sj_arr[j];
            sc = (sc >= 0.f) ? sc : NEG_SLOPE * sc;
            acc = fmaf(expf(sc - m), proj[(size_t)j * OUT_F + lane], acc);
        }
    }
    float h = acc / psum;
    if (f32o) ((float*)outv)[(size_t)row * OUT_F + lane] = h;
    else ((unsigned short*)outv)[(size_t)row * OUT_F + lane] = f2bf(h);
}

extern "C" void kernel_launch(void* const* d_in, const int* in_sizes, int n_in,
                              void* d_out, int out_size, void* d_ws, size_t ws_size,
                              hipStream_t stream) {
    const void* X   = d_in[0];  // [8192,256] fp32 (runtime-detected; bf16 fallback)
    const void* adj = d_in[1];  // [8192,8192] bool as int32 (runtime-detected)
    const void* W   = d_in[2];  // [256,64]
    const void* A   = d_in[3];  // [128,1]

    char* ws = (char*)d_ws;
    float* si    = (float*)ws;
    float* sj    = (float*)(ws + 32768);
    float* proj  = (float*)(ws + 65536);
    int*   gflag = (int*)(ws + (3 << 20));

    hipMemsetAsync(gflag, 0, 8, stream);
    detect_kernel<<<8, 256, 0, stream>>>((const unsigned int*)adj,
                                         (const unsigned short*)X, gflag);
    proj_kernel<<<N_NODES / 16, 256, 0, stream>>>(X, W, A, gflag, proj, si, sj);
    attn_kernel<<<N_NODES / 4, 256, 0, stream>>>(adj, gflag, proj, si, sj, d_out);
}